// Round 5
// baseline (384.262 us; speedup 1.0000x reference)
//
#include <hip/hip_runtime.h>
#include <math.h>

// Problem dims (fixed by reference)
constexpr int cB = 8, cH = 512, cL = 4096, cN = 32;
constexpr int cG = 32, cLC = 128;            // 32 chunks of 128 along L
constexpr int cHN = cH * cN;                 // 16384

// Workspace layout (float offsets)
constexpr size_t OF_RR  = 0;
constexpr size_t OF_RI  = (size_t)cHN;
constexpr size_t OF_RPR = (size_t)2*cHN;     // r^128
constexpr size_t OF_RPI = (size_t)3*cHN;
constexpr size_t OF_C2R = (size_t)4*cHN;     // 2*Cs
constexpr size_t OF_C2I = (size_t)5*cHN;
constexpr size_t OF_DR  = (size_t)6*cHN;     // dt*Ar
constexpr size_t OF_DI  = (size_t)7*cHN;     // dt*Ai
constexpr size_t OF_K   = (size_t)8*cHN;                  // (unused now, kept for layout)
constexpr size_t OF_WP  = OF_K + (size_t)512*128;         // bf16 W packed: 1024*512 ush
constexpr size_t OF_A   = OF_WP + (size_t)1024*512/2;     // bf16 A=[T|Er|-Ei]: [512][128][192] ush
constexpr size_t OF_V   = OF_A + (size_t)512*128*192/2;   // bf16 V: [512][64][128] ush
constexpr size_t OF_XP  = OF_V + (size_t)512*64*128/2;    // bf16 states: [512][256][64] ush
constexpr size_t OF_G   = OF_XP + (size_t)512*256*64/2;   // bf16 g: [B][H][L] ush
// gT (bf16 [B][L][H], 33.5MB) overlays OF_A..OF_XP (dead after k_conv; 50MB available)
constexpr size_t OF_GT  = OF_A;

typedef __bf16 bf16x8 __attribute__((ext_vector_type(8)));
typedef float  f32x4  __attribute__((ext_vector_type(4)));

static __device__ __forceinline__ ushort f2bf(float x) {
    unsigned u = __float_as_uint(x);
    unsigned r = (u + 0x7fffu + ((u >> 16) & 1u)) >> 16;   // RNE
    return (ushort)r;
}
static __device__ __forceinline__ float bf2f(ushort v) {
    return __uint_as_float(((unsigned)v) << 16);
}
static __device__ __forceinline__ unsigned pk2(float a, float b) {
    return (unsigned)f2bf(a) | ((unsigned)f2bf(b) << 16);
}
static __device__ __forceinline__ float gelu(float v) {
    return 0.5f * v * (1.0f + erff(v * 0.70710678118654752f));
}

// ---------------- K0: per-(h,n) constants + V matrix (fused) ----------------
__global__ void k_init(const float* __restrict__ log_dt,
                       const float* __restrict__ log_A_real,
                       const float* __restrict__ A_imag,
                       const float* __restrict__ Cin,
                       float* __restrict__ ws, ushort* __restrict__ wsu)
{
    int tid = blockIdx.x * 256 + threadIdx.x;
    if (tid >= cHN) return;
    int h = tid >> 5, n = tid & 31;
    float dt = expf(log_dt[h]);
    float Ar = -expf(log_A_real[tid]);
    float Ai = A_imag[tid];
    float dr = dt * Ar, di = dt * Ai;
    float er = expf(dr);
    float rr = er * cosf(di), ri = er * sinf(di);
    float erL = expf(dr * (float)cLC);
    float diL = di * (float)cLC;
    float rpr = erL * cosf(diL), rpi = erL * sinf(diL);
    float cr = Cin[2*tid], ci = Cin[2*tid+1];
    float nr = rr - 1.0f, ni = ri;
    float inv = 1.0f / (Ar*Ar + Ai*Ai);
    float wr = (nr*Ar + ni*Ai) * inv;
    float wi = (ni*Ar - nr*Ai) * inv;
    float csr = cr*wr - ci*wi;
    float csi = cr*wi + ci*wr;
    ws[OF_RR  + tid] = rr;  ws[OF_RI  + tid] = ri;
    ws[OF_RPR + tid] = rpr; ws[OF_RPI + tid] = rpi;
    ws[OF_C2R + tid] = 2.0f*csr; ws[OF_C2I + tid] = 2.0f*csi;
    ws[OF_DR  + tid] = dr;  ws[OF_DI  + tid] = di;

    // V matrix: V[h][n][j]=Re(r^(127-j)), [h][32+n][j]=Im
    float e127 = expf(dr * 127.f), a127 = di * 127.f;
    float pr = e127 * cosf(a127), pi_ = e127 * sinf(a127);
    float rie = expf(-dr);
    float rc = rie * cosf(di), rs = -rie * sinf(di);
    ushort* vre = wsu + 2*OF_V + ((size_t)h*64 + n) * 128;
    ushort* vim = wsu + 2*OF_V + ((size_t)h*64 + 32 + n) * 128;
    for (int j4 = 0; j4 < 128; j4 += 4) {
        ushort4 r4, i4;
        #pragma unroll
        for (int e = 0; e < 4; ++e) {
            ((ushort*)&r4)[e] = f2bf(pr);
            ((ushort*)&i4)[e] = f2bf(pi_);
            float npr = pr*rc - pi_*rs;
            float npi = pr*rs + pi_*rc;
            pr = npr; pi_ = npi;
        }
        *(ushort4*)&vre[j4] = r4;
        *(ushort4*)&vim[j4] = i4;
    }
}

// ---------------- pack W -> bf16 with GLU row interleave ----------------
__global__ void k_pack_w(const float* __restrict__ W, ushort* __restrict__ Wp)
{
    int idx = blockIdx.x * 256 + threadIdx.x;
    int base = idx * 4;
    int m = base >> 9;
    int k = base & 511;
    int src = (m & 1) ? (512 + (m >> 1)) : (m >> 1);
    float4 v = *(const float4*)&W[(size_t)src * 512 + k];
    ushort4 o;
    o.x = f2bf(v.x); o.y = f2bf(v.y); o.z = f2bf(v.z); o.w = f2bf(v.w);
    *(ushort4*)&Wp[base] = o;
}

// ---------------- E matrix + k vector + Toeplitz fill (fused) ----------------
__global__ void k_ematT(const float* __restrict__ ws, const float* __restrict__ Dvec,
                        ushort* __restrict__ wsu)
{
    __shared__ float kv[256];
    int t = threadIdx.x;
    int tid = blockIdx.x * 256 + t;             // 65536
    int h = tid >> 7, l = t & 127;
    float fl = (float)l, fl1 = (float)(l + 1);
    const float* dr_ = ws + OF_DR + (size_t)h*32;
    const float* di_ = ws + OF_DI + (size_t)h*32;
    const float* c2r_ = ws + OF_C2R + (size_t)h*32;
    const float* c2i_ = ws + OF_C2I + (size_t)h*32;
    ushort* rowA = wsu + 2*OF_A + ((size_t)h*128 + l) * 192;
    float kacc = 0.f;
    for (int n4 = 0; n4 < 32; n4 += 4) {
        ushort4 prq, npq;
        #pragma unroll
        for (int e = 0; e < 4; ++e) {
            int n = n4 + e;
            float dr = dr_[n], di = di_[n], c2r = c2r_[n], c2i = c2i_[n];
            float e0 = expf(dr * fl), a0 = di * fl;
            float c0 = cosf(a0), s0 = sinf(a0);
            kacc += e0 * (c2r*c0 - c2i*s0);
            float e1 = expf(dr * fl1), a1 = di * fl1;
            float c1 = cosf(a1), s1 = sinf(a1);
            ((ushort*)&prq)[e] = f2bf(e1 * (c2r*c1 - c2i*s1));
            ((ushort*)&npq)[e] = f2bf(-e1 * (c2r*s1 + c2i*c1));
        }
        *(ushort4*)&rowA[128 + n4] = prq;
        *(ushort4*)&rowA[160 + n4] = npq;
    }
    kv[t] = kacc;
    __syncthreads();
    const float* krow = kv + ((t >> 7) << 7);
    float Dh = Dvec[h];
    for (int j8 = 0; j8 < 128; j8 += 8) {
        uint4 qv;
        unsigned w[4];
        #pragma unroll
        for (int p = 0; p < 4; ++p) {
            int j0 = j8 + 2*p, j1 = j0 + 1;
            float v0 = (j0 <= l) ? krow[l - j0] : 0.f;
            float v1 = (j1 <= l) ? krow[l - j1] : 0.f;
            if (j0 == l) v0 += Dh;
            if (j1 == l) v1 += Dh;
            w[p] = pk2(v0, v1);
        }
        qv.x = w[0]; qv.y = w[1]; qv.z = w[2]; qv.w = w[3];
        *(uint4*)&rowA[j8] = qv;
    }
}

// ---------------- State GEMM: per (h, col-half), Xp[h][col][comp] = V*u ----------------
__global__ __launch_bounds__(256) void k_state_gemm(const float* __restrict__ u,
                                                    const ushort* __restrict__ wsu,
                                                    ushort* __restrict__ xp)
{
    __shared__ ushort Vs[64 * 136];
    __shared__ ushort Bsm[128 * 40];
    const int t = threadIdx.x;
    const int h = blockIdx.x;
    const int half = blockIdx.y;
    const int wn = t >> 6, lane = t & 63;
    const int lm = lane & 15, q = lane >> 4;

    {   // stage V[h]: 64x128 bf16
        int row = t >> 2, seg = (t & 3) * 32;
        const ushort* src = wsu + 2*OF_V + ((size_t)h*64 + row) * 128 + seg;
        ushort* d = Vs + row * 136 + seg;
        #pragma unroll
        for (int i = 0; i < 4; ++i) *(uint4*)&d[8*i] = *(const uint4*)&src[8*i];
    }

    const int cl = t & 127;
    const int gc = half * 128 + cl;
    const int bb = gc >> 5, cc = gc & 31;
    const int kh = (t >> 7) * 16;
    f32x4 acc[4][2];
    #pragma unroll
    for (int i = 0; i < 4; ++i)
        #pragma unroll
        for (int j = 0; j < 2; ++j) acc[i][j] = (f32x4){0.f,0.f,0.f,0.f};

    for (int k0 = 0; k0 < 128; k0 += 32) {
        const float* up = u + ((size_t)(bb*cH + h)) * cL + (size_t)cc*128 + k0 + kh;
        float4 f0 = *(const float4*)&up[0],  f1 = *(const float4*)&up[4];
        float4 f2 = *(const float4*)&up[8],  f3 = *(const float4*)&up[12];
        __syncthreads();
        ushort* d = Bsm + cl * 40 + kh;
        uint4 w0, w1;
        w0.x = pk2(f0.x,f0.y); w0.y = pk2(f0.z,f0.w);
        w0.z = pk2(f1.x,f1.y); w0.w = pk2(f1.z,f1.w);
        w1.x = pk2(f2.x,f2.y); w1.y = pk2(f2.z,f2.w);
        w1.z = pk2(f3.x,f3.y); w1.w = pk2(f3.z,f3.w);
        *(uint4*)&d[0] = w0; *(uint4*)&d[8] = w1;
        __syncthreads();
        bf16x8 af[4], bfr[2];
        #pragma unroll
        for (int mi = 0; mi < 4; ++mi)
            af[mi] = *(const bf16x8*)&Vs[(16*mi + lm) * 136 + k0 + 8*q];
        #pragma unroll
        for (int ni = 0; ni < 2; ++ni)
            bfr[ni] = *(const bf16x8*)&Bsm[(32*wn + 16*ni + lm) * 40 + 8*q];
        #pragma unroll
        for (int mi = 0; mi < 4; ++mi)
            #pragma unroll
            for (int ni = 0; ni < 2; ++ni)
                acc[mi][ni] = __builtin_amdgcn_mfma_f32_16x16x32_bf16(af[mi], bfr[ni], acc[mi][ni], 0,0,0);
    }
    #pragma unroll
    for (int mi = 0; mi < 4; ++mi)
        #pragma unroll
        for (int ni = 0; ni < 2; ++ni) {
            int col = half*128 + 32*wn + 16*ni + lm;
            int comp = 16*mi + 4*q;
            ushort4 st;
            st.x = f2bf(acc[mi][ni][0]); st.y = f2bf(acc[mi][ni][1]);
            st.z = f2bf(acc[mi][ni][2]); st.w = f2bf(acc[mi][ni][3]);
            *(ushort4*)&xp[((size_t)h*256 + col) * 64 + comp] = st;
        }
}

// ---------------- Scan: batched loads -> register scan -> batched stores ----------------
__global__ __launch_bounds__(256) void k_scan2(const float* __restrict__ ws,
                                               ushort* __restrict__ xp)
{
    int tid = blockIdx.x * 256 + threadIdx.x;   // B*H*N = 131072
    int n  = tid & 31;
    int bh = tid >> 5;
    int h  = bh & (cH - 1);
    int b  = bh >> 9;
    float rpr = ws[OF_RPR + (size_t)h*32 + n];
    float rpi = ws[OF_RPI + (size_t)h*32 + n];
    ushort* base = xp + ((size_t)h*256 + (size_t)b*32) * 64 + n;
    float sr[32], si[32];
    #pragma unroll
    for (int c = 0; c < 32; ++c) {
        sr[c] = bf2f(base[(size_t)c*64]);
        si[c] = bf2f(base[(size_t)c*64 + 32]);
    }
    float Xr = 0.f, Xi = 0.f;
    #pragma unroll
    for (int c = 0; c < 32; ++c) {
        float tr = sr[c], ti = si[c];
        sr[c] = Xr; si[c] = Xi;
        float nXr = fmaf(rpr, Xr, fmaf(-rpi, Xi, tr));
        float nXi = fmaf(rpr, Xi, fmaf(rpi, Xr, ti));
        Xr = nXr; Xi = nXi;
    }
    #pragma unroll
    for (int c = 0; c < 32; ++c) {
        base[(size_t)c*64]      = f2bf(sr[c]);
        base[(size_t)c*64 + 32] = f2bf(si[c]);
    }
}

// ---------------- Conv GEMM: per (h, coltile): g = gelu(A[128x192] * [u;xr;xi]) ----------------
__global__ __launch_bounds__(256) void k_conv(const float* __restrict__ u,
                                              const ushort* __restrict__ wsu,
                                              ushort* __restrict__ g)
{
    __shared__ ushort As[128 * 40];
    __shared__ ushort Bs[128 * 40];
    const int t = threadIdx.x;
    const int ctile = blockIdx.x;     // 0..1
    const int h = blockIdx.y;
    const int wave = t >> 6, lane = t & 63;
    const int wm = wave & 1, wn = wave >> 1;
    const int lm = lane & 15, q = lane >> 4;

    const int arow = t & 127, ah = t >> 7;
    const int col = arow, half = ah;
    const int gc = ctile * 128 + col;
    const int ub = gc >> 5, uc = gc & 31;

    const ushort* Ab = wsu + 2*OF_A + ((size_t)h*128 + arow) * 192;
    const ushort* xpB = wsu + 2*OF_XP + ((size_t)h*256 + gc) * 64;

    f32x4 acc[4][4];
    #pragma unroll
    for (int i = 0; i < 4; ++i)
        #pragma unroll
        for (int j = 0; j < 4; ++j) acc[i][j] = (f32x4){0.f,0.f,0.f,0.f};

    for (int k0 = 0; k0 < 192; k0 += 32) {
        uint4 a0 = *(const uint4*)&Ab[k0 + 16*ah];
        uint4 a1 = *(const uint4*)&Ab[k0 + 16*ah + 8];
        uint4 b0, b1;
        if (k0 < 128) {
            const float* up = u + ((size_t)(ub*cH + h)) * cL + (size_t)uc*128 + k0 + 16*half;
            float4 f0 = *(const float4*)&up[0],  f1 = *(const float4*)&up[4];
            float4 f2 = *(const float4*)&up[8],  f3 = *(const float4*)&up[12];
            b0.x = pk2(f0.x,f0.y); b0.y = pk2(f0.z,f0.w);
            b0.z = pk2(f1.x,f1.y); b0.w = pk2(f1.z,f1.w);
            b1.x = pk2(f2.x,f2.y); b1.y = pk2(f2.z,f2.w);
            b1.z = pk2(f3.x,f3.y); b1.w = pk2(f3.z,f3.w);
        } else {
            const ushort* xs = xpB + (k0 - 128) + 16*half;
            b0 = *(const uint4*)&xs[0];
            b1 = *(const uint4*)&xs[8];
        }
        __syncthreads();
        *(uint4*)&As[arow*40 + 16*ah]     = a0;
        *(uint4*)&As[arow*40 + 16*ah + 8] = a1;
        *(uint4*)&Bs[col*40 + 16*half]     = b0;
        *(uint4*)&Bs[col*40 + 16*half + 8] = b1;
        __syncthreads();
        bool skip = (wm == 0) && (k0 == 64 || k0 == 96);
        if (!skip) {
            bf16x8 af[4], bfr[4];
            #pragma unroll
            for (int mi = 0; mi < 4; ++mi)
                af[mi] = *(const bf16x8*)&As[(64*wm + 16*mi + lm) * 40 + 8*q];
            #pragma unroll
            for (int ni = 0; ni < 4; ++ni)
                bfr[ni] = *(const bf16x8*)&Bs[(64*wn + 16*ni + lm) * 40 + 8*q];
            #pragma unroll
            for (int mi = 0; mi < 4; ++mi)
                #pragma unroll
                for (int ni = 0; ni < 4; ++ni)
                    acc[mi][ni] = __builtin_amdgcn_mfma_f32_16x16x32_bf16(af[mi], bfr[ni], acc[mi][ni], 0,0,0);
        }
    }
    #pragma unroll
    for (int ni = 0; ni < 4; ++ni) {
        int ocol = ctile*128 + 64*wn + 16*ni + lm;
        int ob = ocol >> 5, oc = ocol & 31;
        ushort* grow = g + ((size_t)(ob*cH + h)) * cL + (size_t)oc*128;
        #pragma unroll
        for (int mi = 0; mi < 4; ++mi) {
            int l = 64*wm + 16*mi + 4*q;
            ushort4 st;
            st.x = f2bf(gelu(acc[mi][ni][0]));
            st.y = f2bf(gelu(acc[mi][ni][1]));
            st.z = f2bf(gelu(acc[mi][ni][2]));
            st.w = f2bf(gelu(acc[mi][ni][3]));
            *(ushort4*)&grow[l] = st;
        }
    }
}

// ---------------- Transpose: g[b][h][l] -> gT[b][l][h] (bf16) ----------------
__global__ __launch_bounds__(256) void k_tr(const ushort* __restrict__ g,
                                            ushort* __restrict__ gT)
{
    __shared__ unsigned Ts[64 * 33];
    const int t = threadIdx.x;
    const int l0 = blockIdx.x * 64;
    const int h0 = blockIdx.y * 64;
    const int b  = blockIdx.z;
    // read: h-pair rows (2hp, 2hp+1), 8 l each; pack pairs into u32
    int hp = t >> 3, lseg = (t & 7) * 8;
    const ushort* r0 = g + ((size_t)(b*cH + h0 + 2*hp) * cL + l0 + lseg);
    const ushort* r1 = r0 + cL;
    uint4 a = *(const uint4*)r0;
    uint4 bq = *(const uint4*)r1;
    const ushort* ap = (const ushort*)&a;
    const ushort* bp = (const ushort*)&bq;
    #pragma unroll
    for (int j = 0; j < 8; ++j) {
        unsigned w = (unsigned)ap[j] | ((unsigned)bp[j] << 16);
        Ts[(lseg + j) * 33 + hp] = w;
    }
    __syncthreads();
    // write: row l, 16 h (8 u32 pairs), coalesced
    int lr = t >> 2, hs = (t & 3) * 8;
    unsigned v[8];
    #pragma unroll
    for (int i = 0; i < 8; ++i) v[i] = Ts[lr * 33 + hs + i];
    uint4 o0, o1;
    o0.x=v[0]; o0.y=v[1]; o0.z=v[2]; o0.w=v[3];
    o1.x=v[4]; o1.y=v[5]; o1.z=v[6]; o1.w=v[7];
    ushort* dst = gT + ((size_t)b * cL + l0 + lr) * cH + h0 + hs*2;
    *(uint4*)&dst[0] = o0;
    *(uint4*)&dst[8] = o1;
}

// ---------------- Big GEMM + bias + GLU, clean staging from gT ----------------
__global__ __launch_bounds__(256, 2) void k_gemm2(const ushort* __restrict__ Wp,
                                                  const float* __restrict__ bias,
                                                  const ushort* __restrict__ gT,
                                                  float* __restrict__ out)
{
    __shared__ ushort As[128 * 72];   // 18.4 KB
    __shared__ ushort Bs[256 * 72];   // 36.9 KB
    const int t = threadIdx.x;
    const int l0 = blockIdx.x * 256;
    const int by = blockIdx.y;
    const int b  = blockIdx.z;
    const int wave = t >> 6, lane = t & 63;
    const int wm = wave & 1, wn = wave >> 1;
    const int lm = lane & 15, q = lane >> 4;
    const int arow = t & 127, ah = (t >> 7) * 32;

    const ushort* wRow = Wp + (size_t)(by*128 + arow) * 512 + ah;
    const ushort* gRow = gT + ((size_t)b * cL + l0 + t) * cH;

    f32x4 acc[4][8];
    #pragma unroll
    for (int i = 0; i < 4; ++i)
        #pragma unroll
        for (int j = 0; j < 8; ++j) acc[i][j] = (f32x4){0.f,0.f,0.f,0.f};

    for (int k0 = 0; k0 < 512; k0 += 64) {
        uint4 wa[4], gb[8];
        #pragma unroll
        for (int i = 0; i < 4; ++i) wa[i] = *(const uint4*)&wRow[k0 + 8*i];
        #pragma unroll
        for (int i = 0; i < 8; ++i) gb[i] = *(const uint4*)&gRow[k0 + 8*i];
        __syncthreads();
        #pragma unroll
        for (int i = 0; i < 4; ++i) *(uint4*)&As[arow*72 + ah + 8*i] = wa[i];
        #pragma unroll
        for (int i = 0; i < 8; ++i) *(uint4*)&Bs[t*72 + 8*i] = gb[i];
        __syncthreads();
        #pragma unroll
        for (int kk = 0; kk < 64; kk += 32) {
            bf16x8 af[4], bfr[8];
            #pragma unroll
            for (int mi = 0; mi < 4; ++mi)
                af[mi] = *(const bf16x8*)&As[(64*wm + 16*mi + lm)*72 + kk + 8*q];
            #pragma unroll
            for (int ni = 0; ni < 8; ++ni)
                bfr[ni] = *(const bf16x8*)&Bs[(128*wn + 16*ni + lm)*72 + kk + 8*q];
            #pragma unroll
            for (int mi = 0; mi < 4; ++mi)
                #pragma unroll
                for (int ni = 0; ni < 8; ++ni)
                    acc[mi][ni] = __builtin_amdgcn_mfma_f32_16x16x32_bf16(af[mi], bfr[ni], acc[mi][ni], 0,0,0);
        }
    }
    // epilogue: packed rows pair in-lane (reg 2p,2p+1) = (a,b)
    const int obase = by*64 + 32*wm;
    const int colb = l0 + 128*wn + lm;
    #pragma unroll
    for (int mi = 0; mi < 4; ++mi) {
        #pragma unroll
        for (int p = 0; p < 2; ++p) {
            int o = obase + 8*mi + 2*q + p;
            float ba = bias[o], bb = bias[512 + o];
            float* orow = out + ((size_t)b * cH + o) * cL + colb;
            #pragma unroll
            for (int ni = 0; ni < 8; ++ni) {
                float av = acc[mi][ni][2*p]     + ba;
                float gv = acc[mi][ni][2*p + 1] + bb;
                orow[16 * ni] = av / (1.f + expf(-gv));
            }
        }
    }
}

extern "C" void kernel_launch(void* const* d_in, const int* in_sizes, int n_in,
                              void* d_out, int out_size, void* d_ws, size_t ws_size,
                              hipStream_t stream)
{
    (void)in_sizes; (void)n_in; (void)out_size; (void)ws_size;
    const float* u          = (const float*)d_in[0];
    const float* log_dt     = (const float*)d_in[1];
    const float* log_A_real = (const float*)d_in[2];
    const float* A_imag     = (const float*)d_in[3];
    const float* C          = (const float*)d_in[4];
    const float* D          = (const float*)d_in[5];
    const float* W          = (const float*)d_in[6];
    const float* bias       = (const float*)d_in[7];
    float* out = (float*)d_out;
    float* ws  = (float*)d_ws;
    ushort* wsu = (ushort*)d_ws;
    ushort* Wp  = wsu + 2*OF_WP;
    ushort* xp  = wsu + 2*OF_XP;
    ushort* gbf = wsu + 2*OF_G;
    ushort* gT  = wsu + 2*OF_GT;

    hipLaunchKernelGGL(k_init, dim3(cHN/256), dim3(256), 0, stream,
                       log_dt, log_A_real, A_imag, C, ws, wsu);
    hipLaunchKernelGGL(k_pack_w, dim3(1024*512/4/256), dim3(256), 0, stream, W, Wp);
    hipLaunchKernelGGL(k_ematT, dim3(512*128/256), dim3(256), 0, stream, ws, D, wsu);
    hipLaunchKernelGGL(k_state_gemm, dim3(512, 2), dim3(256), 0, stream, u, wsu, xp);
    hipLaunchKernelGGL(k_scan2, dim3(cB*cH*cN/256), dim3(256), 0, stream, ws, xp);
    hipLaunchKernelGGL(k_conv, dim3(2, 512), dim3(256), 0, stream, u, wsu, gbf);
    hipLaunchKernelGGL(k_tr, dim3(cL/64, cH/64, cB), dim3(256), 0, stream, gbf, gT);
    hipLaunchKernelGGL(k_gemm2, dim3(cL/256, 1024/128, cB), dim3(256), 0, stream,
                       Wp, bias, gT, out);
}